// Round 13
// baseline (43.380 us; speedup 1.0000x reference)
//
#include <hip/hip_runtime.h>

#define CI 32
#define CO 32
#define PD 64
#define QDIM 1024
#define M_TOTAL (32*4096)
#define TILE_M 256                 // per WG: 4 waves x 2 row-blocks x 32 rows
#define NBLK (M_TOTAL/TILE_M)      // 512 WGs -> 2 per CU, 1 generation
#define WG_THREADS 256
#define CHUNK_I 4                  // i's per A-chunk
#define NCHUNK (CI/CHUNK_I)        // 8
#define CHUNK_ELEMS (CHUNK_I*2048) // 8192 bf16 = 16 KB per buffer

typedef float  f32x4  __attribute__((ext_vector_type(4)));
typedef float  f32x16 __attribute__((ext_vector_type(16)));
typedef __bf16 bf16x4 __attribute__((ext_vector_type(4)));
typedef __bf16 bf16x8 __attribute__((ext_vector_type(8)));

#define XLS 257    // Xl[i][m]: conflict-free lane-scalar reads (lanes->distinct banks)
#define OLS 33     // Ol[m][o]: <=2-way on writes

// ---- one-time: Wk [64][1024] f32 -> wsF, the A-panel layout ----
// wsF elem idx = (q>>5)*2048 + (k>>3)*256 + (q&31)*8 + (k&7)  [bf16]
// = exact MFMA A-fragment order: per i, frag f, lane (l31,hi) reads contiguous
//   wsF + i*2048 + (2f+hi)*256 + l31*8   (1024 B per wave-instr)
__global__ __launch_bounds__(256)
void wk_pack_kernel(const float* __restrict__ Wk, __bf16* __restrict__ wsF)
{
    __shared__ float tile[64][33];
    const int q0 = blockIdx.x * 32;
    const int t  = threadIdx.x;
#pragma unroll
    for (int s = 0; s < 2; ++s) {
        const int idx = t + s * 256;
        const int k = idx >> 3, ch = idx & 7;
        f32x4 v = *(const f32x4*)(Wk + (size_t)k * QDIM + q0 + ch * 4);
        tile[k][ch*4+0] = v[0]; tile[k][ch*4+1] = v[1];
        tile[k][ch*4+2] = v[2]; tile[k][ch*4+3] = v[3];
    }
    __syncthreads();
    const int qq = t >> 3;          // 0..31
    const int g  = t & 7;           // k-octet
    bf16x8 o;
#pragma unroll
    for (int j = 0; j < 8; ++j) o[j] = (__bf16)tile[g*8 + j][qq];
    *(bf16x8*)(wsF + (size_t)blockIdx.x * 2048 + g * 256 + qq * 8) = o;
}

// Swapped-operand scheme (R11/R12) + LDS-staged A via global_load_lds:
// all 8 waves/CU read A from LDS instead of each privately streaming the
// 128KB wsF through L1/L2 (R12's residual stall). wsF layout is already
// fragment-linear -> DMA dest linear, ds_reads linear, no swizzle.
// P-tile, A-dbuf, and O-staging have sequential lifetimes -> one union.
__global__ __launch_bounds__(WG_THREADS, 2)
void cond_dense_kernel(const float* __restrict__ Xg, const float* __restrict__ Pg,
                       const __bf16* __restrict__ wsF, float* __restrict__ outg)
{
    __shared__ union {
        __bf16 p[TILE_M * PD];          // 32768 B: P-tile (until bfrag extracted)
        __bf16 a[2][CHUNK_ELEMS];       // 32768 B: A chunk double-buffer (i-loop)
        float  o[TILE_M * OLS];         // 33792 B: output staging (after i-loop)
    } U;
    __shared__ float Xl[CI * XLS];      // 32896 B: X transposed [i][m]

    const int tid = threadIdx.x;
    const int l   = tid & 63;
    const int w   = tid >> 6;       // wave 0..3 -> rows w*64 .. w*64+63
    const int l31 = l & 31;
    const int hi  = l >> 5;         // k-half within K=16 MFMA
    const int mlo = w * 64 + l31;
    const int mhi = mlo + 32;
    const int tile0 = blockIdx.x * TILE_M;

    // ---- phase 1: stage P[256][64]->bf16 swizzled LDS; X[256][32]->Xl[i][m] ----
    {
        const float* Pb = Pg + (size_t)tile0 * PD;
        const int pr = tid >> 4, pch = tid & 15;
#pragma unroll
        for (int s = 0; s < 16; ++s) {
            const int r = pr + s * 16;
            f32x4 v = *(const f32x4*)(Pb + (size_t)r * PD + pch * 4);
            bf16x4 bv;
#pragma unroll
            for (int j = 0; j < 4; ++j) bv[j] = (__bf16)v[j];
            char* dst = (char*)U.p + r * 128
                      + ((((pch >> 1) ^ (r & 7)) << 4) | ((pch & 1) * 8));
            *(bf16x4*)dst = bv;
        }
        const float* Xb = Xg + (size_t)tile0 * CI;
        const int xr = tid >> 3, xch = tid & 7;
#pragma unroll
        for (int s = 0; s < 8; ++s) {
            const int r = xr + s * 32;
            f32x4 v = *(const f32x4*)(Xb + (size_t)r * CI + xch * 4);
#pragma unroll
            for (int j = 0; j < 4; ++j)
                Xl[(xch * 4 + j) * XLS + r] = v[j];
        }
    }
    __syncthreads();

    // ---- B fragments (P^T) for both row-blocks: 32 VGPR, loop-invariant ----
    bf16x8 bfA[4], bfB[4];
#pragma unroll
    for (int kq = 0; kq < 4; ++kq) {
        const int g = ((kq * 2 + hi) ^ (mlo & 7)) << 4;   // mhi&7 == mlo&7
        bfA[kq] = *(const bf16x8*)((const char*)U.p + mlo * 128 + g);
        bfB[kq] = *(const bf16x8*)((const char*)U.p + mhi * 128 + g);
    }
    __syncthreads();   // all waves done reading U.p -> U.a may be written

    // ---- A-chunk DMA staging (linear dest = wave base + lane*16) ----
    auto stageA = [&](int c, int b) {
        const __bf16* src = wsF + (size_t)c * CHUNK_ELEMS + tid * 8;
        __bf16* dst = U.a[b] + tid * 8;
#pragma unroll
        for (int s = 0; s < 4; ++s)   // 4 x (256 thr x 16 B) = 16 KB
            __builtin_amdgcn_global_load_lds(
                (const __attribute__((address_space(1))) void*)(src + s * 2048),
                (__attribute__((address_space(3))) void*)(dst + s * 2048),
                16, 0, 0);
    };

    f32x16 oA = {}, oB = {};

    stageA(0, 0);
    __syncthreads();   // chunk 0 landed (vmcnt drained by barrier)

    for (int c = 0; c < NCHUNK; ++c) {
        if (c + 1 < NCHUNK) stageA(c + 1, (c + 1) & 1);  // in flight during compute
        const __bf16* ab = U.a[c & 1];
#pragma unroll
        for (int il = 0; il < CHUNK_I; ++il) {
            const int i = c * CHUNK_I + il;
            const __bf16* ap = ab + il * 2048 + hi * 256 + l31 * 8;
            bf16x8 a0 = *(const bf16x8*)(ap);          // frag f=0
            bf16x8 a1 = *(const bf16x8*)(ap +  512);   // f=1
            bf16x8 a2 = *(const bf16x8*)(ap + 1024);   // f=2
            bf16x8 a3 = *(const bf16x8*)(ap + 1536);   // f=3
            const float xl = Xl[i * XLS + mlo];
            const float xh = Xl[i * XLS + mhi];
            f32x16 cA = {}, cB = {};
            cA = __builtin_amdgcn_mfma_f32_32x32x16_bf16(a0, bfA[0], cA, 0, 0, 0);
            cB = __builtin_amdgcn_mfma_f32_32x32x16_bf16(a0, bfB[0], cB, 0, 0, 0);
            cA = __builtin_amdgcn_mfma_f32_32x32x16_bf16(a1, bfA[1], cA, 0, 0, 0);
            cB = __builtin_amdgcn_mfma_f32_32x32x16_bf16(a1, bfB[1], cB, 0, 0, 0);
            cA = __builtin_amdgcn_mfma_f32_32x32x16_bf16(a2, bfA[2], cA, 0, 0, 0);
            cB = __builtin_amdgcn_mfma_f32_32x32x16_bf16(a2, bfB[2], cB, 0, 0, 0);
            cA = __builtin_amdgcn_mfma_f32_32x32x16_bf16(a3, bfA[3], cA, 0, 0, 0);
            cB = __builtin_amdgcn_mfma_f32_32x32x16_bf16(a3, bfB[3], cB, 0, 0, 0);
#pragma unroll
            for (int r = 0; r < 16; ++r) {
                oA[r] += fmaxf(cA[r], 0.0f) * xl;
                oB[r] += fmaxf(cB[r], 0.0f) * xh;
            }
        }
        __syncthreads();   // next chunk landed; this buffer free for c+2
    }

    // ---- stage output (U.a dead): lane row m, o = (r&3)+8*(r>>2)+4*hi ----
#pragma unroll
    for (int r = 0; r < 16; ++r) {
        const int o = (r & 3) + 8 * (r >> 2) + 4 * hi;
        U.o[mlo * OLS + o] = oA[r];
        U.o[mhi * OLS + o] = oB[r];
    }
    __syncthreads();

    // ---- coalesced store: 8 x f32x4 per thread, full 128B lines ----
    {
        const int sr = tid >> 3, sch = (tid & 7) * 4;
#pragma unroll
        for (int s = 0; s < 8; ++s) {
            const int r = sr + s * 32;
            f32x4 v;
#pragma unroll
            for (int j = 0; j < 4; ++j) v[j] = U.o[r * OLS + sch + j];
            *(f32x4*)(outg + (size_t)(tile0 + r) * CO + sch) = v;
        }
    }
}

extern "C" void kernel_launch(void* const* d_in, const int* in_sizes, int n_in,
                              void* d_out, int out_size, void* d_ws, size_t ws_size,
                              hipStream_t stream)
{
    const float* X  = (const float*)d_in[0];
    const float* P  = (const float*)d_in[1];
    const float* Wk = (const float*)d_in[2];
    float* out = (float*)d_out;
    __bf16* wsF = (__bf16*)d_ws;   // 1024*64*2 = 128 KB

    wk_pack_kernel<<<dim3(QDIM / 32), dim3(256), 0, stream>>>(Wk, wsF);
    cond_dense_kernel<<<dim3(NBLK), dim3(WG_THREADS), 0, stream>>>(X, P, wsF, out);
}